// Round 1
// baseline (936.164 us; speedup 1.0000x reference)
//
#include <hip/hip_runtime.h>

#define NH 8
#define HD 32
#define NL 4
#define NP 4
#define DM 256
#define LEN_IN_C 13294
#define LQ_C 13294
#define B_C 2
#define M_TOTAL (B_C * LQ_C)   // 26588

// ---------------------------------------------------------------------------
// Simple LDS-tiled fp32 GEMM:  C[M,N] = A[M,K] @ B[K,N] + bias[N]
// N, K multiples of 16; M ragged (guarded).
// ---------------------------------------------------------------------------
__global__ void gemm_bias_kernel(const float* __restrict__ A,
                                 const float* __restrict__ B,
                                 const float* __restrict__ bias,
                                 float* __restrict__ C,
                                 int M, int N, int K) {
    __shared__ float As[16][16];
    __shared__ float Bs[16][17];   // +1 pad
    const int tx = threadIdx.x, ty = threadIdx.y;
    const int row = blockIdx.y * 16 + ty;
    const int col = blockIdx.x * 16 + tx;
    float acc = 0.0f;
    for (int k0 = 0; k0 < K; k0 += 16) {
        As[ty][tx] = (row < M) ? A[(size_t)row * K + k0 + tx] : 0.0f;
        Bs[ty][tx] = B[(size_t)(k0 + ty) * N + col];   // col < N always (grid covers N)
        __syncthreads();
#pragma unroll
        for (int kk = 0; kk < 16; ++kk)
            acc += As[ty][kk] * Bs[kk][tx];
        __syncthreads();
    }
    if (row < M)
        C[(size_t)row * N + col] = acc + bias[col];
}

// ---------------------------------------------------------------------------
// Sampling kernel: one 256-thread block per (b,q).
//   tid = h*32 + d   (h: head 0..7, d: dim 0..31)
// Does the softmax over 16 (level,point) logits per head, then the bilinear
// gather-accumulate. Writes acc in layout [b][q][h*32+d] = [b][q][256].
// ---------------------------------------------------------------------------
__global__ void msda_sample_kernel(const float* __restrict__ ref_pts, // [B][LQ][4][2]
                                   const float* __restrict__ value,   // [B][LEN_IN][NH][HD]
                                   const float* __restrict__ offs,    // [B][LQ][256]
                                   const float* __restrict__ attn,    // [B][LQ][128] (logits)
                                   float* __restrict__ acc_out)       // [B][LQ][256]
{
    constexpr int lvl_h[4] = {100, 50, 25, 13};
    constexpr int lvl_w[4] = {100, 50, 25, 13};
    constexpr int lvl_s[4] = {0, 10000, 12500, 13125};

    const int bq = blockIdx.x;           // 0 .. B*LQ-1
    const int b  = bq / LQ_C;
    const int tid = threadIdx.x;
    const int h  = tid >> 5;
    const int d  = tid & 31;

    __shared__ float s_off[256];
    __shared__ float s_attn[128];
    __shared__ float s_ref[8];

    s_off[tid] = offs[(size_t)bq * 256 + tid];
    if (tid < 128) s_attn[tid] = attn[(size_t)bq * 128 + tid];
    if (tid < 8)   s_ref[tid]  = ref_pts[(size_t)bq * 8 + tid];
    __syncthreads();

    // softmax per head over its 16 logits (one lane per head)
    if (d == 0) {
        float* a = &s_attn[h * 16];
        float m = a[0];
#pragma unroll
        for (int i = 1; i < 16; ++i) m = fmaxf(m, a[i]);
        float s = 0.0f;
#pragma unroll
        for (int i = 0; i < 16; ++i) { float e = expf(a[i] - m); a[i] = e; s += e; }
        float inv = 1.0f / s;
#pragma unroll
        for (int i = 0; i < 16; ++i) a[i] *= inv;
    }
    __syncthreads();

    float acc = 0.0f;
    const float* vbase = value + (size_t)b * LEN_IN_C * DM;

#pragma unroll
    for (int l = 0; l < NL; ++l) {
        const int hh = lvl_h[l], ww = lvl_w[l], s0 = lvl_s[l];
        const float fw = (float)ww, fh = (float)hh;
        const float rx = s_ref[l * 2 + 0], ry = s_ref[l * 2 + 1];
#pragma unroll
        for (int p = 0; p < NP; ++p) {
            const int oi = ((h * NL + l) * NP + p) * 2;
            const float lx = rx + s_off[oi]     / fw;
            const float ly = ry + s_off[oi + 1] / fh;
            const float x = lx * fw - 0.5f;
            const float y = ly * fh - 0.5f;
            const float x0 = floorf(x), y0 = floorf(y);
            const float tx = x - x0, ty = y - y0;
            const int ix0 = (int)x0, iy0 = (int)y0;

            const bool xv0 = (ix0 >= 0)     && (ix0 < ww);
            const bool xv1 = (ix0 + 1 >= 0) && (ix0 + 1 < ww);
            const bool yv0 = (iy0 >= 0)     && (iy0 < hh);
            const bool yv1 = (iy0 + 1 >= 0) && (iy0 + 1 < hh);

            float v00 = 0.0f, v01 = 0.0f, v10 = 0.0f, v11 = 0.0f;
            if (yv0) {
                const float* rowp = vbase + (size_t)(s0 + iy0 * ww) * DM + h * HD + d;
                if (xv0) v00 = rowp[(ptrdiff_t)ix0 * DM];
                if (xv1) v01 = rowp[(ptrdiff_t)(ix0 + 1) * DM];
            }
            if (yv1) {
                const float* rowp = vbase + (size_t)(s0 + (iy0 + 1) * ww) * DM + h * HD + d;
                if (xv0) v10 = rowp[(ptrdiff_t)ix0 * DM];
                if (xv1) v11 = rowp[(ptrdiff_t)(ix0 + 1) * DM];
            }
            const float samp = v00 * (1.0f - tx) * (1.0f - ty)
                             + v01 * tx          * (1.0f - ty)
                             + v10 * (1.0f - tx) * ty
                             + v11 * tx          * ty;
            acc += s_attn[h * 16 + l * NP + p] * samp;
        }
    }
    acc_out[(size_t)bq * 256 + tid] = acc;
}

extern "C" void kernel_launch(void* const* d_in, const int* in_sizes, int n_in,
                              void* d_out, int out_size, void* d_ws, size_t ws_size,
                              hipStream_t stream) {
    const float* query  = (const float*)d_in[0];
    const float* refp   = (const float*)d_in[1];
    const float* inflat = (const float*)d_in[2];
    // d_in[3] = input_spatial_shapes (int32) — shapes are compile-time constants here
    const float* Wv    = (const float*)d_in[4];
    const float* bv    = (const float*)d_in[5];
    const float* Woff  = (const float*)d_in[6];
    const float* boff  = (const float*)d_in[7];
    const float* Wattn = (const float*)d_in[8];
    const float* battn = (const float*)d_in[9];
    const float* Wout  = (const float*)d_in[10];
    const float* bout  = (const float*)d_in[11];
    float* out = (float*)d_out;

    float* ws    = (float*)d_ws;
    float* value = ws;                                   // M*256 floats
    float* offs  = value + (size_t)M_TOTAL * 256;        // M*256
    float* attn  = offs  + (size_t)M_TOTAL * 256;        // M*128
    float* acc   = attn  + (size_t)M_TOTAL * 128;        // M*256

    const int M = M_TOTAL;
    dim3 blk(16, 16);
    dim3 g256(256 / 16, (M + 15) / 16);
    dim3 g128(128 / 16, (M + 15) / 16);

    gemm_bias_kernel<<<g256, blk, 0, stream>>>(inflat, Wv,    bv,    value, M, 256, 256);
    gemm_bias_kernel<<<g256, blk, 0, stream>>>(query,  Woff,  boff,  offs,  M, 256, 256);
    gemm_bias_kernel<<<g128, blk, 0, stream>>>(query,  Wattn, battn, attn,  M, 128, 256);
    msda_sample_kernel<<<dim3(M), dim3(256), 0, stream>>>(refp, value, offs, attn, acc);
    gemm_bias_kernel<<<g256, blk, 0, stream>>>(acc, Wout, bout, out, M, 256, 256);
}

// Round 2
// 245.872 us; speedup vs baseline: 3.8075x; 3.8075x over previous
//
#include <hip/hip_runtime.h>

#define NH 8
#define HD 32
#define NL 4
#define NP 4
#define DM 256
#define LEN_IN_C 13294
#define LQ_C 13294
#define B_C 2
#define M_TOTAL (B_C * LQ_C)           // 26588
#define MT_TILES 1662                  // ceil(26588/16)
#define MP_ROWS (MT_TILES * 16)        // 26592

typedef __attribute__((ext_vector_type(8))) short short8;
typedef __attribute__((ext_vector_type(4))) float floatx4;

__device__ __forceinline__ unsigned short f2bf(float x) {
    union { float f; unsigned int u; } a; a.f = x;
    unsigned int r = (a.u + 0x7FFFu + ((a.u >> 16) & 1u)) >> 16;
    return (unsigned short)r;
}
__device__ __forceinline__ float bf2f(unsigned short b) {
    union { unsigned int u; float f; } a; a.u = ((unsigned int)b) << 16;
    return a.f;
}

// ---------------------------------------------------------------------------
// Convert A [M,256] fp32 row-major -> swizzled bf16 fragments.
// Unit u = (rt*8 + kc)*64 + lane; lane = m + 16*q holds A[rt*16+m][kc*32+q*8+j].
// ---------------------------------------------------------------------------
__global__ __launch_bounds__(256) void conv_a_kernel(const float* __restrict__ A,
                                                     unsigned short* __restrict__ Asw,
                                                     int M) {
    const int u = blockIdx.x * 256 + threadIdx.x;
    const int lane = u & 63;
    const int kc = (u >> 6) & 7;
    const int rt = u >> 9;
    const int row = rt * 16 + (lane & 15);
    const int col0 = kc * 32 + (lane >> 4) * 8;
    unsigned short tmp[8];
    if (row < M) {
        const float4 f0 = *(const float4*)(A + (size_t)row * 256 + col0);
        const float4 f1 = *(const float4*)(A + (size_t)row * 256 + col0 + 4);
        tmp[0] = f2bf(f0.x); tmp[1] = f2bf(f0.y); tmp[2] = f2bf(f0.z); tmp[3] = f2bf(f0.w);
        tmp[4] = f2bf(f1.x); tmp[5] = f2bf(f1.y); tmp[6] = f2bf(f1.z); tmp[7] = f2bf(f1.w);
    } else {
#pragma unroll
        for (int j = 0; j < 8; ++j) tmp[j] = 0;
    }
    short8 v;
#pragma unroll
    for (int j = 0; j < 8; ++j) v[j] = (short)tmp[j];
    ((short8*)Asw)[u] = v;
}

// ---------------------------------------------------------------------------
// Convert B [K=256, Nsrc] fp32 -> swizzled bf16 fragments at n-tile offset.
// Dst unit = (kc*NTtotal + ntOff + ntl)*64 + lane; lane = n + 16*q holds
// B[kc*32 + q*8 + j][ntl*16 + n].
// ---------------------------------------------------------------------------
__global__ __launch_bounds__(256) void conv_b_kernel(const float* __restrict__ W,
                                                     unsigned short* __restrict__ Bsw,
                                                     int Nsrc, int NTsrc, int NTtotal, int ntOff) {
    const int u = blockIdx.x * 256 + threadIdx.x;
    const int lane = u & 63;
    const int unit = u >> 6;
    const int ntl = unit % NTsrc;
    const int kc = unit / NTsrc;
    const int n = ntl * 16 + (lane & 15);
    const int k0 = kc * 32 + (lane >> 4) * 8;
    short8 v;
#pragma unroll
    for (int j = 0; j < 8; ++j)
        v[j] = (short)f2bf(W[(size_t)(k0 + j) * Nsrc + n]);
    ((short8*)Bsw)[(size_t)(kc * NTtotal + ntOff + ntl) * 64 + lane] = v;
}

__global__ void fuse_bias_kernel(const float* __restrict__ b0, const float* __restrict__ b1,
                                 float* __restrict__ fb) {
    const int t = threadIdx.x;
    if (t < 384) fb[t] = (t < 256) ? b0[t] : b1[t - 256];
}

// ---------------------------------------------------------------------------
// Register-only MFMA GEMM: C[M, NT*16] = A[M,256] @ B[256, NT*16] + bias.
// Block = 4 waves, 2 row-tiles (32 rows); wave w covers n-tiles [w*NTW, +NTW).
// A/B pre-swizzled bf16 fragments; no LDS, no barriers.
// ---------------------------------------------------------------------------
template <int NT, bool OUT_BF16>
__global__ __launch_bounds__(256) void mfma_gemm_kernel(const unsigned short* __restrict__ Asw,
                                                        const unsigned short* __restrict__ Bsw,
                                                        const float* __restrict__ bias,
                                                        void* __restrict__ Cout, int M) {
    constexpr int NTW = NT / 4;
    const int tid = threadIdx.x;
    const int lane = tid & 63;
    const int wave = tid >> 6;
    const int rt0 = blockIdx.x * 2;

    const short8* Au = (const short8*)Asw;
    const short8* Bu = (const short8*)Bsw;

    floatx4 acc[2][NTW];
#pragma unroll
    for (int r = 0; r < 2; ++r)
#pragma unroll
        for (int t = 0; t < NTW; ++t) acc[r][t] = (floatx4){0.f, 0.f, 0.f, 0.f};

#pragma unroll 2
    for (int kc = 0; kc < 8; ++kc) {
        const short8 a0 = Au[(size_t)(rt0 * 8 + kc) * 64 + lane];
        const short8 a1 = Au[(size_t)((rt0 + 1) * 8 + kc) * 64 + lane];
#pragma unroll
        for (int t = 0; t < NTW; ++t) {
            const short8 b = Bu[(size_t)(kc * NT + wave * NTW + t) * 64 + lane];
            acc[0][t] = __builtin_amdgcn_mfma_f32_16x16x32_bf16(a0, b, acc[0][t], 0, 0, 0);
            acc[1][t] = __builtin_amdgcn_mfma_f32_16x16x32_bf16(a1, b, acc[1][t], 0, 0, 0);
        }
    }

    const int N = NT * 16;
    const int colq = lane & 15;
    const int rowq = (lane >> 4) * 4;
#pragma unroll
    for (int t = 0; t < NTW; ++t) {
        const int col = (wave * NTW + t) * 16 + colq;
        const float bc = bias[col];
#pragma unroll
        for (int r = 0; r < 2; ++r) {
            const int rowb = (rt0 + r) * 16 + rowq;
#pragma unroll
            for (int reg = 0; reg < 4; ++reg) {
                const int row = rowb + reg;
                if (row < M) {
                    const float v = acc[r][t][reg] + bc;
                    if (OUT_BF16)
                        ((unsigned short*)Cout)[(size_t)row * N + col] = f2bf(v);
                    else
                        ((float*)Cout)[(size_t)row * N + col] = v;
                }
            }
        }
    }
}

// ---------------------------------------------------------------------------
// Sampler: one 256-thread block per (b,q).
// Phase 1 (tid<128): per-(h,l,p) softmax (16-lane shfl) + precompute 4 clamped
//   flat indices and 4 attn-premultiplied bilinear weights into LDS.
// Phase 2: tid = h*32+d accumulates 16 points x 4 corners from bf16 value.
// Output written directly in swizzled bf16 A-fragment layout for the out-GEMM.
// ---------------------------------------------------------------------------
__global__ __launch_bounds__(256) void msda_sample_kernel(const float* __restrict__ refp,
                                                          const unsigned short* __restrict__ value,
                                                          const float* __restrict__ fused,
                                                          unsigned short* __restrict__ AccSw) {
    constexpr int lvl_hw[4] = {100, 50, 25, 13};
    constexpr int lvl_s[4] = {0, 10000, 12500, 13125};

    const int bq = blockIdx.x;
    const int b = (bq >= LQ_C) ? 1 : 0;
    const int tid = threadIdx.x;

    __shared__ float s_ref[8];
    __shared__ int4 s_pi[128];
    __shared__ float4 s_pw[128];

    if (tid < 8) s_ref[tid] = refp[(size_t)bq * 8 + tid];
    __syncthreads();

    if (tid < 128) {
        const int t = tid;
        const int h = t >> 4;
        const int l = (t >> 2) & 3;

        // softmax over the 16 (l,p) logits of head h (lanes t = h*16 .. h*16+15)
        const float logit = fused[(size_t)bq * 384 + 256 + t];
        float m = logit;
#pragma unroll
        for (int mask = 1; mask < 16; mask <<= 1) m = fmaxf(m, __shfl_xor(m, mask));
        const float e = expf(logit - m);
        float s = e;
#pragma unroll
        for (int mask = 1; mask < 16; mask <<= 1) s += __shfl_xor(s, mask);
        const float aw = e / s;

        const int whl = lvl_hw[l];
        const float fwh = (float)whl;
        const float ox = fused[(size_t)bq * 384 + t * 2];
        const float oy = fused[(size_t)bq * 384 + t * 2 + 1];
        const float x = s_ref[l * 2] * fwh + ox - 0.5f;
        const float y = s_ref[l * 2 + 1] * fwh + oy - 0.5f;
        const float x0f = floorf(x), y0f = floorf(y);
        const float tx = x - x0f, ty = y - y0f;
        const int ix0 = (int)x0f, iy0 = (int)y0f;

        const bool xv0 = (unsigned)ix0 < (unsigned)whl;
        const bool xv1 = (unsigned)(ix0 + 1) < (unsigned)whl;
        const bool yv0 = (unsigned)iy0 < (unsigned)whl;
        const bool yv1 = (unsigned)(iy0 + 1) < (unsigned)whl;

        const int cx0 = min(max(ix0, 0), whl - 1);
        const int cx1 = min(max(ix0 + 1, 0), whl - 1);
        const int cy0 = min(max(iy0, 0), whl - 1);
        const int cy1 = min(max(iy0 + 1, 0), whl - 1);

        const int base = (b * LEN_IN_C + lvl_s[l]) * 256 + h * 32;
        const int r0 = base + cy0 * (whl * 256);
        const int r1 = base + cy1 * (whl * 256);
        int4 ii;
        ii.x = r0 + cx0 * 256;
        ii.y = r0 + cx1 * 256;
        ii.z = r1 + cx0 * 256;
        ii.w = r1 + cx1 * 256;
        float4 wv;
        wv.x = (xv0 && yv0) ? aw * (1.f - tx) * (1.f - ty) : 0.f;
        wv.y = (xv1 && yv0) ? aw * tx * (1.f - ty) : 0.f;
        wv.z = (xv0 && yv1) ? aw * (1.f - tx) * ty : 0.f;
        wv.w = (xv1 && yv1) ? aw * tx * ty : 0.f;
        s_pi[t] = ii;
        s_pw[t] = wv;
    }
    __syncthreads();

    const int h = tid >> 5;
    const int d = tid & 31;
    float acc = 0.0f;
#pragma unroll
    for (int pt = 0; pt < 16; ++pt) {
        const int pp = h * 16 + pt;
        const int4 ii = s_pi[pp];
        const float4 wv = s_pw[pp];
        const float v00 = bf2f(value[ii.x + d]);
        const float v01 = bf2f(value[ii.y + d]);
        const float v10 = bf2f(value[ii.z + d]);
        const float v11 = bf2f(value[ii.w + d]);
        acc += wv.x * v00 + wv.y * v01 + wv.z * v10 + wv.w * v11;
    }

    // write swizzled: row=bq, col=tid
    const int rt = bq >> 4, mm = bq & 15;
    const int kc = tid >> 5, q = (tid >> 3) & 3, j = tid & 7;
    AccSw[((size_t)(rt * 8 + kc) * 64 + (q * 16 + mm)) * 8 + j] = f2bf(acc);
}

extern "C" void kernel_launch(void* const* d_in, const int* in_sizes, int n_in,
                              void* d_out, int out_size, void* d_ws, size_t ws_size,
                              hipStream_t stream) {
    const float* query  = (const float*)d_in[0];
    const float* refp   = (const float*)d_in[1];
    const float* inflat = (const float*)d_in[2];
    const float* Wv    = (const float*)d_in[4];
    const float* bv    = (const float*)d_in[5];
    const float* Woff  = (const float*)d_in[6];
    const float* boff  = (const float*)d_in[7];
    const float* Wattn = (const float*)d_in[8];
    const float* battn = (const float*)d_in[9];
    const float* Wout  = (const float*)d_in[10];
    const float* bout  = (const float*)d_in[11];
    float* out = (float*)d_out;

    // workspace layout (all 16B aligned)
    char* p = (char*)d_ws;
    const size_t aswBytes = (size_t)MT_TILES * 8 * 64 * 8 * sizeof(unsigned short); // 13.6 MB
    unsigned short* AswQ = (unsigned short*)p;           p += aswBytes;
    unsigned short* AswS = (unsigned short*)p;           p += aswBytes;  // AswV then AccSw
    unsigned short* BswV = (unsigned short*)p;           p += (size_t)8 * 16 * 64 * 8 * 2;
    unsigned short* BswOA = (unsigned short*)p;          p += (size_t)8 * 24 * 64 * 8 * 2;
    unsigned short* BswO = (unsigned short*)p;           p += (size_t)8 * 16 * 64 * 8 * 2;
    float* fbias = (float*)p;                            p += 384 * sizeof(float);
    unsigned short* value = (unsigned short*)p;          p += (size_t)M_TOTAL * 256 * 2;
    float* fused = (float*)p;                            p += (size_t)M_TOTAL * 384 * 4;

    const int M = M_TOTAL;
    const int convABlocks = MT_TILES * 2;   // MT*512 threads / 256

    // weight conversions
    conv_b_kernel<<<32, 256, 0, stream>>>(Wv,    BswV,  256, 16, 16, 0);
    conv_b_kernel<<<32, 256, 0, stream>>>(Woff,  BswOA, 256, 16, 24, 0);
    conv_b_kernel<<<16, 256, 0, stream>>>(Wattn, BswOA, 128,  8, 24, 16);
    conv_b_kernel<<<32, 256, 0, stream>>>(Wout,  BswO,  256, 16, 16, 0);
    fuse_bias_kernel<<<1, 384, 0, stream>>>(boff, battn, fbias);

    // activation conversions
    conv_a_kernel<<<convABlocks, 256, 0, stream>>>(inflat, AswS, M);
    conv_a_kernel<<<convABlocks, 256, 0, stream>>>(query,  AswQ, M);

    const int gemmBlocks = MT_TILES / 2;    // 831
    // value = inflat @ Wv + bv   (bf16 out)
    mfma_gemm_kernel<16, true><<<gemmBlocks, 256, 0, stream>>>(AswS, BswV, bv, value, M);
    // fused = query @ [Woff|Wattn] + [boff|battn]   (fp32 out)
    mfma_gemm_kernel<24, false><<<gemmBlocks, 256, 0, stream>>>(AswQ, BswOA, fbias, fused, M);
    // sampling -> swizzled bf16 acc (reuses AswS region)
    msda_sample_kernel<<<M, 256, 0, stream>>>(refp, value, fused, AswS);
    // out = acc @ Wout + bout
    mfma_gemm_kernel<16, false><<<gemmBlocks, 256, 0, stream>>>(AswS, BswO, bout, out, M);
}

// Round 3
// 230.819 us; speedup vs baseline: 4.0558x; 1.0652x over previous
//
#include <hip/hip_runtime.h>

#define NH 8
#define HD 32
#define NL 4
#define NP 4
#define DM 256
#define LEN_IN_C 13294
#define LQ_C 13294
#define B_C 2
#define M_TOTAL (B_C * LQ_C)           // 26588
#define MT_TILES 1662                  // ceil(26588/16)

typedef __attribute__((ext_vector_type(8))) short short8;
typedef __attribute__((ext_vector_type(4))) float floatx4;

__device__ __forceinline__ unsigned short f2bf(float x) {
    union { float f; unsigned int u; } a; a.f = x;
    unsigned int r = (a.u + 0x7FFFu + ((a.u >> 16) & 1u)) >> 16;
    return (unsigned short)r;
}
__device__ __forceinline__ float bflo(unsigned int u) {
    union { unsigned int u; float f; } a; a.u = u << 16; return a.f;
}
__device__ __forceinline__ float bfhi(unsigned int u) {
    union { unsigned int u; float f; } a; a.u = u & 0xffff0000u; return a.f;
}

// ---------------------------------------------------------------------------
// Convert A [M,256] fp32 row-major -> swizzled bf16 fragments.
// Unit u = (rt*8 + kc)*64 + lane; lane = m + 16*q holds A[rt*16+m][kc*32+q*8+j].
// grid.y selects (src0->dst0) or (src1->dst1).
// ---------------------------------------------------------------------------
__global__ __launch_bounds__(256) void conv_a_kernel(const float* __restrict__ A0,
                                                     unsigned short* __restrict__ D0,
                                                     const float* __restrict__ A1,
                                                     unsigned short* __restrict__ D1,
                                                     int M) {
    const float* A = blockIdx.y ? A1 : A0;
    unsigned short* Asw = blockIdx.y ? D1 : D0;
    const int u = blockIdx.x * 256 + threadIdx.x;
    const int lane = u & 63;
    const int kc = (u >> 6) & 7;
    const int rt = u >> 9;
    const int row = rt * 16 + (lane & 15);
    const int col0 = kc * 32 + (lane >> 4) * 8;
    unsigned short tmp[8];
    if (row < M) {
        const float4 f0 = *(const float4*)(A + (size_t)row * 256 + col0);
        const float4 f1 = *(const float4*)(A + (size_t)row * 256 + col0 + 4);
        tmp[0] = f2bf(f0.x); tmp[1] = f2bf(f0.y); tmp[2] = f2bf(f0.z); tmp[3] = f2bf(f0.w);
        tmp[4] = f2bf(f1.x); tmp[5] = f2bf(f1.y); tmp[6] = f2bf(f1.z); tmp[7] = f2bf(f1.w);
    } else {
#pragma unroll
        for (int j = 0; j < 8; ++j) tmp[j] = 0;
    }
    short8 v;
#pragma unroll
    for (int j = 0; j < 8; ++j) v[j] = (short)tmp[j];
    ((short8*)Asw)[u] = v;
}

// ---------------------------------------------------------------------------
// All weight conversions + bias fuse in ONE kernel (one launch).
// ---------------------------------------------------------------------------
__device__ __forceinline__ void conv_b_body(const float* __restrict__ W,
                                            unsigned short* __restrict__ Bsw,
                                            int Nsrc, int NTsrc, int NTtotal, int ntOff,
                                            int vblk) {
    const int u = vblk * 256 + threadIdx.x;
    const int lane = u & 63;
    const int unit = u >> 6;
    const int ntl = unit % NTsrc;
    const int kc = unit / NTsrc;
    const int n = ntl * 16 + (lane & 15);
    const int k0 = kc * 32 + (lane >> 4) * 8;
    short8 v;
#pragma unroll
    for (int j = 0; j < 8; ++j)
        v[j] = (short)f2bf(W[(size_t)(k0 + j) * Nsrc + n]);
    ((short8*)Bsw)[(size_t)(kc * NTtotal + ntOff + ntl) * 64 + lane] = v;
}

__global__ __launch_bounds__(256) void conv_weights_kernel(const float* __restrict__ Wv,
                                                           const float* __restrict__ Woff,
                                                           const float* __restrict__ Wattn,
                                                           const float* __restrict__ Wout,
                                                           const float* __restrict__ boff,
                                                           const float* __restrict__ battn,
                                                           unsigned short* __restrict__ BswV,
                                                           unsigned short* __restrict__ BswOA,
                                                           unsigned short* __restrict__ BswO,
                                                           float* __restrict__ fbias) {
    const int blk = blockIdx.x;
    if (blk < 32)        conv_b_body(Wv,    BswV,  256, 16, 16, 0,  blk);
    else if (blk < 64)   conv_b_body(Woff,  BswOA, 256, 16, 24, 0,  blk - 32);
    else if (blk < 80)   conv_b_body(Wattn, BswOA, 128,  8, 24, 16, blk - 64);
    else if (blk < 112)  conv_b_body(Wout,  BswO,  256, 16, 16, 0,  blk - 80);
    else {
        const int t = (blk - 112) * 256 + threadIdx.x;
        if (t < 384) fbias[t] = (t < 256) ? boff[t] : battn[t - 256];
    }
}

// ---------------------------------------------------------------------------
// Register-only MFMA GEMM: C[M, NT*16] = A[M,256] @ B[256, NT*16] + bias.
// ---------------------------------------------------------------------------
template <int NT, bool OUT_BF16>
__global__ __launch_bounds__(256) void mfma_gemm_kernel(const unsigned short* __restrict__ Asw,
                                                        const unsigned short* __restrict__ Bsw,
                                                        const float* __restrict__ bias,
                                                        void* __restrict__ Cout, int M) {
    constexpr int NTW = NT / 4;
    const int tid = threadIdx.x;
    const int lane = tid & 63;
    const int wave = tid >> 6;
    const int rt0 = blockIdx.x * 2;

    const short8* Au = (const short8*)Asw;
    const short8* Bu = (const short8*)Bsw;

    floatx4 acc[2][NTW];
#pragma unroll
    for (int r = 0; r < 2; ++r)
#pragma unroll
        for (int t = 0; t < NTW; ++t) acc[r][t] = (floatx4){0.f, 0.f, 0.f, 0.f};

#pragma unroll 2
    for (int kc = 0; kc < 8; ++kc) {
        const short8 a0 = Au[(size_t)(rt0 * 8 + kc) * 64 + lane];
        const short8 a1 = Au[(size_t)((rt0 + 1) * 8 + kc) * 64 + lane];
#pragma unroll
        for (int t = 0; t < NTW; ++t) {
            const short8 b = Bu[(size_t)(kc * NT + wave * NTW + t) * 64 + lane];
            acc[0][t] = __builtin_amdgcn_mfma_f32_16x16x32_bf16(a0, b, acc[0][t], 0, 0, 0);
            acc[1][t] = __builtin_amdgcn_mfma_f32_16x16x32_bf16(a1, b, acc[1][t], 0, 0, 0);
        }
    }

    const int N = NT * 16;
    const int colq = lane & 15;
    const int rowq = (lane >> 4) * 4;
#pragma unroll
    for (int t = 0; t < NTW; ++t) {
        const int col = (wave * NTW + t) * 16 + colq;
        const float bc = bias[col];
#pragma unroll
        for (int r = 0; r < 2; ++r) {
            const int rowb = (rt0 + r) * 16 + rowq;
#pragma unroll
            for (int reg = 0; reg < 4; ++reg) {
                const int row = rowb + reg;
                if (row < M) {
                    const float v = acc[r][t][reg] + bc;
                    if (OUT_BF16)
                        ((unsigned short*)Cout)[(size_t)row * N + col] = f2bf(v);
                    else
                        ((float*)Cout)[(size_t)row * N + col] = v;
                }
            }
        }
    }
}

// ---------------------------------------------------------------------------
// Sampler v3: one 256-thread block per 4 queries.
//   Phase 1: 512 point-jobs (4q x 128 pts) over 256 threads (2 each):
//     softmax (16-lane shfl) + 4 clamped BYTE offsets + 4 premult weights -> LDS
//     (per-head stride padded 16->17 to spread broadcast groups across banks).
//   Phase 2: tid = qq*64 + h*8 + l8; lane owns 4 dims via one uint2 (4 bf16)
//     load per corner. 2 accumulators to break the FMA chain.
//   Output written directly in swizzled bf16 A-fragment layout (uint2 store).
// ---------------------------------------------------------------------------
__global__ __launch_bounds__(256, 6) void msda_sample_kernel(const float* __restrict__ refp,
                                                             const unsigned short* __restrict__ value,
                                                             const float* __restrict__ fused,
                                                             unsigned short* __restrict__ AccSw) {
    constexpr int lvl_hw[4] = {100, 50, 25, 13};
    constexpr int lvl_s[4] = {0, 10000, 12500, 13125};

    const int bq0 = blockIdx.x * 4;
    const int tid = threadIdx.x;

    __shared__ float s_ref[32];
    __shared__ int4 s_pi[4 * 8 * 17];
    __shared__ float4 s_pw[4 * 8 * 17];

    if (tid < 32) s_ref[tid] = refp[(size_t)bq0 * 8 + tid];
    __syncthreads();

#pragma unroll
    for (int jj = 0; jj < 2; ++jj) {
        const int job = jj * 256 + tid;          // 0..511
        const int qq = job >> 7;                 // 0..3
        const int t = job & 127;                 // point id within query
        const int h = t >> 4;
        const int l = (t >> 2) & 3;
        const int bq = bq0 + qq;
        const int b = (bq >= LQ_C) ? 1 : 0;

        // softmax over the 16 (l,p) logits of head h
        const float logit = fused[(size_t)bq * 384 + 256 + t];
        float m = logit;
#pragma unroll
        for (int mask = 1; mask < 16; mask <<= 1) m = fmaxf(m, __shfl_xor(m, mask));
        const float e = expf(logit - m);
        float s = e;
#pragma unroll
        for (int mask = 1; mask < 16; mask <<= 1) s += __shfl_xor(s, mask);
        const float aw = e / s;

        const int whl = lvl_hw[l];
        const float fwh = (float)whl;
        const float2 oxy = *(const float2*)(fused + (size_t)bq * 384 + t * 2);
        const float x = s_ref[qq * 8 + l * 2] * fwh + oxy.x - 0.5f;
        const float y = s_ref[qq * 8 + l * 2 + 1] * fwh + oxy.y - 0.5f;
        const float x0f = floorf(x), y0f = floorf(y);
        const float tx = x - x0f, ty = y - y0f;
        const int ix0 = (int)x0f, iy0 = (int)y0f;

        const bool xv0 = (unsigned)ix0 < (unsigned)whl;
        const bool xv1 = (unsigned)(ix0 + 1) < (unsigned)whl;
        const bool yv0 = (unsigned)iy0 < (unsigned)whl;
        const bool yv1 = (unsigned)(iy0 + 1) < (unsigned)whl;

        const int cx0 = min(max(ix0, 0), whl - 1);
        const int cx1 = min(max(ix0 + 1, 0), whl - 1);
        const int cy0 = min(max(iy0, 0), whl - 1);
        const int cy1 = min(max(iy0 + 1, 0), whl - 1);

        const int base = (b * LEN_IN_C + lvl_s[l]) * 256 + h * 32;
        const int r0 = base + cy0 * (whl * 256);
        const int r1 = base + cy1 * (whl * 256);
        int4 ii;                                  // BYTE offsets
        ii.x = (r0 + cx0 * 256) * 2;
        ii.y = (r0 + cx1 * 256) * 2;
        ii.z = (r1 + cx0 * 256) * 2;
        ii.w = (r1 + cx1 * 256) * 2;
        float4 wv;
        wv.x = (xv0 && yv0) ? aw * (1.f - tx) * (1.f - ty) : 0.f;
        wv.y = (xv1 && yv0) ? aw * tx * (1.f - ty) : 0.f;
        wv.z = (xv0 && yv1) ? aw * (1.f - tx) * ty : 0.f;
        wv.w = (xv1 && yv1) ? aw * tx * ty : 0.f;
        const int slot = (qq * 8 + h) * 17 + (t & 15);
        s_pi[slot] = ii;
        s_pw[slot] = wv;
    }
    __syncthreads();

    const int qq = tid >> 6;
    const int h = (tid >> 3) & 7;
    const int l8 = tid & 7;          // owns dims 4*l8 .. 4*l8+3
    const int d4 = l8 * 8;           // byte offset within head block
    const char* vb = (const char*)value;
    const int pbase = (qq * 8 + h) * 17;

    float4 acc0 = {0.f, 0.f, 0.f, 0.f};
    float4 acc1 = {0.f, 0.f, 0.f, 0.f};
#pragma unroll 2
    for (int pt = 0; pt < 16; ++pt) {
        const int4 ii = s_pi[pbase + pt];
        const float4 wv = s_pw[pbase + pt];
        const uint2 v00 = *(const uint2*)(vb + (ii.x + d4));
        const uint2 v01 = *(const uint2*)(vb + (ii.y + d4));
        const uint2 v10 = *(const uint2*)(vb + (ii.z + d4));
        const uint2 v11 = *(const uint2*)(vb + (ii.w + d4));
        acc0.x += wv.x * bflo(v00.x); acc0.y += wv.x * bfhi(v00.x);
        acc0.z += wv.x * bflo(v00.y); acc0.w += wv.x * bfhi(v00.y);
        acc1.x += wv.y * bflo(v01.x); acc1.y += wv.y * bfhi(v01.x);
        acc1.z += wv.y * bflo(v01.y); acc1.w += wv.y * bfhi(v01.y);
        acc0.x += wv.z * bflo(v10.x); acc0.y += wv.z * bfhi(v10.x);
        acc0.z += wv.z * bflo(v10.y); acc0.w += wv.z * bfhi(v10.y);
        acc1.x += wv.w * bflo(v11.x); acc1.y += wv.w * bfhi(v11.x);
        acc1.z += wv.w * bflo(v11.y); acc1.w += wv.w * bfhi(v11.y);
    }
    const float4 acc = {acc0.x + acc1.x, acc0.y + acc1.y, acc0.z + acc1.z, acc0.w + acc1.w};

    // write swizzled A-fragment: row = bq0+qq, col = h*32 + 4*l8 (+0..3)
    const int bq = bq0 + qq;
    const int rt = bq >> 4, mm = bq & 15;
    const int col = h * 32 + l8 * 4;
    const int kc = col >> 5, q2 = (col >> 3) & 3, j = col & 7;
    unsigned int p0 = (unsigned int)f2bf(acc.x) | ((unsigned int)f2bf(acc.y) << 16);
    unsigned int p1 = (unsigned int)f2bf(acc.z) | ((unsigned int)f2bf(acc.w) << 16);
    uint2 pk; pk.x = p0; pk.y = p1;
    *(uint2*)(AccSw + ((size_t)((rt * 8 + kc) * 64 + (q2 * 16 + mm)) * 8 + j)) = pk;
}

extern "C" void kernel_launch(void* const* d_in, const int* in_sizes, int n_in,
                              void* d_out, int out_size, void* d_ws, size_t ws_size,
                              hipStream_t stream) {
    const float* query  = (const float*)d_in[0];
    const float* refp   = (const float*)d_in[1];
    const float* inflat = (const float*)d_in[2];
    const float* Wv    = (const float*)d_in[4];
    const float* bv    = (const float*)d_in[5];
    const float* Woff  = (const float*)d_in[6];
    const float* boff  = (const float*)d_in[7];
    const float* Wattn = (const float*)d_in[8];
    const float* battn = (const float*)d_in[9];
    const float* Wout  = (const float*)d_in[10];
    const float* bout  = (const float*)d_in[11];
    float* out = (float*)d_out;

    char* p = (char*)d_ws;
    const size_t aswBytes = (size_t)MT_TILES * 8 * 64 * 8 * sizeof(unsigned short); // 13.6 MB
    unsigned short* AswQ = (unsigned short*)p;           p += aswBytes;
    unsigned short* AswS = (unsigned short*)p;           p += aswBytes;  // AswV then AccSw
    unsigned short* BswV = (unsigned short*)p;           p += (size_t)8 * 16 * 64 * 8 * 2;
    unsigned short* BswOA = (unsigned short*)p;          p += (size_t)8 * 24 * 64 * 8 * 2;
    unsigned short* BswO = (unsigned short*)p;           p += (size_t)8 * 16 * 64 * 8 * 2;
    float* fbias = (float*)p;                            p += 384 * sizeof(float);
    unsigned short* value = (unsigned short*)p;          p += (size_t)M_TOTAL * 256 * 2;
    float* fused = (float*)p;                            p += (size_t)M_TOTAL * 384 * 4;

    const int M = M_TOTAL;

    conv_weights_kernel<<<114, 256, 0, stream>>>(Wv, Woff, Wattn, Wout, boff, battn,
                                                 BswV, BswOA, BswO, fbias);
    conv_a_kernel<<<dim3(MT_TILES * 2, 2), 256, 0, stream>>>(inflat, AswS, query, AswQ, M);

    const int gemmBlocks = MT_TILES / 2;    // 831
    mfma_gemm_kernel<16, true><<<gemmBlocks, 256, 0, stream>>>(AswS, BswV, bv, value, M);
    mfma_gemm_kernel<24, false><<<gemmBlocks, 256, 0, stream>>>(AswQ, BswOA, fbias, fused, M);
    msda_sample_kernel<<<M / 4, 256, 0, stream>>>(refp, value, fused, AswS);
    mfma_gemm_kernel<16, false><<<gemmBlocks, 256, 0, stream>>>(AswS, BswO, bout, out, M);
}